// Round 1
// baseline (188.988 us; speedup 1.0000x reference)
//
#include <hip/hip_runtime.h>

// Problem constants (fixed shape: B=1, H=2048, W=3072)
constexpr int Wd  = 3072;
constexpr int WC  = 14;     // window size
constexpr int XL  = 12;     // x front pad (need >=10; 12 keeps float4 alignment)
constexpr int XR  = 16;     // x tail pad (need >=13 data zeros; 16 rounds float4 reads)
constexpr int ZL  = 16;     // z front pad (need >=14; 16 keeps float4 alignment)

// Each block handles one row h. 256 threads, each computes 4 consecutive
// outputs per pass, 3 passes (3072 = 256*4*3). All global stores are
// coalesced float4. LDS halo reads are aligned ds_read_b128 into registers.
__global__ __launch_bounds__(256)
void color_restore_kernel(const float* __restrict__ xg,
                          const float* __restrict__ zg,
                          float* __restrict__ out, int Hn)
{
    __shared__ __align__(16) float xs[XL + Wd + XR]; // 3100 floats
    __shared__ __align__(16) float zs[ZL + Wd];      // 3088 floats

    const int h = blockIdx.x;
    const int t = threadIdx.x;

    // ---- stage row into LDS (coalesced float4) ----
    const float4* xrow = (const float4*)(xg + (size_t)h * Wd);
    const float4* zrow = (const float4*)(zg + (size_t)h * Wd);
    float4* xs4 = (float4*)(xs + XL);
    float4* zs4 = (float4*)(zs + ZL);
#pragma unroll
    for (int i = 0; i < 3; ++i) {
        const int idx = t + i * 256;   // 768 float4 per row
        xs4[idx] = xrow[idx];
        zs4[idx] = zrow[idx];
    }
    if (t < XL) xs[t] = 0.f;                    // x front zeros
    if (t < XR) xs[XL + Wd + t] = 0.f;          // x tail zeros
    if (t < ZL) zs[t] = 0.f;                    // z front zeros
    __syncthreads();

    const int plane = Hn * Wd;           // 6291456, fits int
    float* yout = out;
    float* rout = out + 3 * (size_t)plane;

#pragma unroll
    for (int p = 0; p < 3; ++p) {
        const int w0 = p * 1024 + 4 * t;

        // ---- pull halo spans from LDS as aligned float4 ----
        // z span needed: j in [w0-13, w0+3]  (17 floats)
        //   abs start = ZL + w0 - 13 = p*1024 + 4t + 3  -> offset 3 in its float4
        float zbuf[20];
        {
            float4* zb = (float4*)zbuf;
            const int zblk = (ZL + w0 - 13) >> 2;  // offset ==3 guaranteed
#pragma unroll
            for (int i = 0; i < 5; ++i) zb[i] = ((const float4*)zs)[zblk + i];
        }
        // x span needed: k in [w0-10, w0+13]  (24 floats)
        //   abs start = XL + w0 - 10 = p*1024 + 4t + 2  -> offset 2 in its float4
        float xbuf[28];
        {
            float4* xb = (float4*)xbuf;
            const int xblk = (XL + w0 - 10) >> 2;  // offset ==2 guaranteed
#pragma unroll
            for (int i = 0; i < 7; ++i) xb[i] = ((const float4*)xs)[xblk + i];
        }
        // Relative indexing: z[w0+d] == zbuf[16+d] (d in [-13,3])
        //                    x[w0+d] == xbuf[12+d] (d in [-10,13])

        // ---- initial 14-tap window at w = w0 ----
        float den = 0.f, n0 = 0.f, n1 = 0.f, n2 = 0.f;
#pragma unroll
        for (int s = 0; s < WC; ++s) {     // j = w0 - 13 + s
            const float zj = zbuf[3 + s];
            den += zj;
            n0 = fmaf(xbuf[s + 2], zj, n0);   // x[j+3]
            n1 = fmaf(xbuf[s + 6], zj, n1);   // x[j+7]
            n2 = fmaf(xbuf[s + 9], zj, n2);   // x[j+10]
        }

        float y0[4], y1[4], y2[4], r0[4], r1[4], r2[4];
#pragma unroll
        for (int q = 0; q < 4; ++q) {      // w = w0 + q
            if (q > 0) {
                const float zin  = zbuf[16 + q];      // z[w]
                const float zot  = zbuf[2 + q];       // z[w-14]
                den += zin - zot;
                n0 += xbuf[15 + q] * zin - xbuf[1 + q] * zot;  // x[w+3],  x[w-11]
                n1 += xbuf[19 + q] * zin - xbuf[5 + q] * zot;  // x[w+7],  x[w-7]
                n2 += xbuf[22 + q] * zin - xbuf[8 + q] * zot;  // x[w+10], x[w-4]
            }
            const float rinv = __builtin_amdgcn_rcpf(den);
            y0[q] = n0 * rinv;
            y1[q] = n1 * rinv;
            y2[q] = n2 * rinv;
            r0[q] = zbuf[13 + q];   // z[w-3]
            r1[q] = zbuf[9 + q];    // z[w-7]
            r2[q] = zbuf[6 + q];    // z[w-10]
        }

        // ---- coalesced float4 stores ----
        const int off = h * Wd + w0;
        *(float4*)(yout + off)             = make_float4(y0[0], y0[1], y0[2], y0[3]);
        *(float4*)(yout + plane + off)     = make_float4(y1[0], y1[1], y1[2], y1[3]);
        *(float4*)(yout + 2 * plane + off) = make_float4(y2[0], y2[1], y2[2], y2[3]);
        *(float4*)(rout + off)             = make_float4(r0[0], r0[1], r0[2], r0[3]);
        *(float4*)(rout + plane + off)     = make_float4(r1[0], r1[1], r1[2], r1[3]);
        *(float4*)(rout + 2 * plane + off) = make_float4(r2[0], r2[1], r2[2], r2[3]);
    }
}

extern "C" void kernel_launch(void* const* d_in, const int* in_sizes, int n_in,
                              void* d_out, int out_size, void* d_ws, size_t ws_size,
                              hipStream_t stream)
{
    const float* x = (const float*)d_in[0];
    const float* z = (const float*)d_in[1];
    float* out = (float*)d_out;
    const int Hn = in_sizes[0] / Wd;   // 2048
    color_restore_kernel<<<dim3(Hn), dim3(256), 0, stream>>>(x, z, out, Hn);
}